// Round 15
// baseline (256.324 us; speedup 1.0000x reference)
//
#include <hip/hip_runtime.h>
#include <hip/hip_bf16.h>
#include <cstdint>
#include <cstddef>

typedef __attribute__((ext_vector_type(8))) short short8;
typedef __attribute__((ext_vector_type(4))) float f32x4;
typedef __attribute__((ext_vector_type(2))) float f32x2;
typedef __attribute__((ext_vector_type(4))) unsigned int u32x4;

#define NDIM 100
#define NSTEP 50
#define NPATH 8192
#define XSTR 128   // X row: position i holds physical dim k(i)=(i&7)*16+(i>>3); dim100=t at pos38

typedef const __attribute__((address_space(1))) unsigned int glb_u32;
typedef __attribute__((address_space(3))) unsigned int lds_u32;

__device__ __forceinline__ unsigned short f2b(float f){
  unsigned int u = __float_as_uint(f);
  u += 0x7fffu + ((u >> 16) & 1u);          // RNE
  return (unsigned short)(u >> 16);
}
__device__ __forceinline__ float b2f(unsigned short h){
  return __uint_as_float(((unsigned int)h) << 16);
}

// 16-lane (DPP row) full reduction via row_ror adds — VALU pipe, no LDS ops.
template<int CTRL>
__device__ __forceinline__ float dpp_add(float x){
  int t = __builtin_amdgcn_update_dpp(0, __float_as_int(x), CTRL, 0xF, 0xF, true);
  return x + __int_as_float(t);
}
__device__ __forceinline__ float rowsum16(float x){
  x = dpp_add<0x128>(x);   // row_ror:8
  x = dpp_add<0x124>(x);   // row_ror:4
  x = dpp_add<0x122>(x);   // row_ror:2
  x = dpp_add<0x121>(x);   // row_ror:1
  return x;
}

// ---------------- combined prep: weights (swizzled LDS image) + params ----------------
// Blocks [0,256): WTS elem ((L*128+n)*16+s)*8+j = W_L[kphys][n], lc=s^(n&15), kphys=j*16+lc.
// Blocks [256,262): PPAR[L][p][c][ct] (p: 0=bias 1=gamma 2=beta; L=3 only bias, padded).
__global__ __launch_bounds__(256) void prep_all(
    const float* __restrict__ W1, const float* __restrict__ W2,
    const float* __restrict__ W3, const float* __restrict__ W4,
    const float* __restrict__ b1, const float* __restrict__ g1, const float* __restrict__ be1,
    const float* __restrict__ b2, const float* __restrict__ g2, const float* __restrict__ be2,
    const float* __restrict__ b3, const float* __restrict__ g3, const float* __restrict__ be3,
    const float* __restrict__ b4,
    unsigned short* __restrict__ WTS, float* __restrict__ PPAR)
{
  if (blockIdx.x < 256){
    int idx = blockIdx.x * 256 + threadIdx.x;   // 65536 weight elems
    int j = idx & 7;
    int s = (idx >> 3) & 15;
    int n = (idx >> 7) & 127;
    int L = idx >> 14;
    int lc = s ^ (n & 15);
    int k  = j * 16 + lc;                       // physical k
    float v;
    if (L == 0)      v = (k <= NDIM) ? W1[k * 128 + n] : 0.f;
    else if (L == 1) v = W2[k * 128 + n];
    else if (L == 2) v = W3[k * 128 + n];
    else             v = (n < NDIM) ? W4[k * NDIM + n] : 0.f;
    WTS[idx] = f2b(v);
    return;
  }
  int idx = (blockIdx.x - 256) * 256 + threadIdx.x;   // 1536 param elems
  if (idx >= 1536) return;
  int ct = idx & 7;
  int c  = (idx >> 3) & 15;
  int p  = (idx >> 7) % 3;
  int L  = idx / 384;
  int col = ct * 16 + c;
  const float* v;
  if (L == 0)      v = (p == 0) ? b1 : (p == 1) ? g1 : be1;
  else if (L == 1) v = (p == 0) ? b2 : (p == 1) ? g2 : be2;
  else if (L == 2) v = (p == 0) ? b3 : (p == 1) ? g3 : be3;
  else             v = b4;
  float val;
  if (L == 3) val = (p == 0 && col < NDIM) ? b4[col] : 0.f;
  else        val = v[col];
  PPAR[idx] = val;
}

// ---------------- Phase A: S-chain scan -> permuted X rows + final S ----------------
// FULL X rows written (pads as zeros) — R14 lesson: holed wave-stores degrade to
// partial-line commits and halve write BW. E is NOT written (epilogue rebuilds it).
__global__ __launch_bounds__(256) void phaseA(
    const float* __restrict__ dw, const float* __restrict__ tg,
    unsigned short* __restrict__ X,
    float* __restrict__ Sout, int path0)
{
  const int pb = threadIdx.x >> 6;
  const int t  = threadIdx.x & 63;
  const int bl = blockIdx.x * 4 + pb;          // chunk-local path
  const int b  = path0 + bl;
  const int d0 = (t & 7) * 16 + (t >> 3);
  const int d1 = d0 + 8;
  float s0 = 100.f, s1 = 100.f;
  const float* dwb = dw + (long)b * NSTEP * NDIM;
  const float* tgb = tg + (long)b * NSTEP;
  unsigned short* Xb = X + (long)bl * NSTEP * XSTR;
  for (int i = 0; i < NSTEP; ++i){
    float tv = tgb[i];
    float w0 = (d0 < NDIM) ? dwb[i * NDIM + d0] : 0.f;
    float w1 = (d1 < NDIM) ? dwb[i * NDIM + d1] : 0.f;
    unsigned short* Xr = Xb + i * XSTR;
    Xr[t]      = (d0 < NDIM) ? f2b(s0 * 0.01f) : ((d0 == NDIM) ? f2b(tv) : (unsigned short)0);
    Xr[t + 64] = (d1 < NDIM) ? f2b(s1 * 0.01f) : (unsigned short)0;   // d1 is never ==100
    s0 = fmaf(s0, 0.001f + 0.2f * w0, s0);
    s1 = fmaf(s1, 0.001f + 0.2f * w1, s1);
  }
  if (d0 < NDIM) Sout[(long)b * NDIM + d0] = s0;
  if (d1 < NDIM) Sout[(long)b * NDIM + d1] = s1;
}

// ---------------- Phase B: fused 4-layer MLP, 2 row-tiles/wave (128 rows/block) ----------------
// R12 body + E reconstructed in epilogue: e[n] = 20 * X[row][pos(n)] * dw[path,step,n]
// (pos = c*8+ct <-> n = ct*16+c). dw re-read is L3-resident (chunk capped at 4096 paths).
__global__ __launch_bounds__(256, 3) void phaseB(
    const unsigned short* __restrict__ X,
    const float* __restrict__ dw,
    const unsigned short* __restrict__ WTS,
    const float* __restrict__ PPAR,
    float* __restrict__ cbuf, long row0, int p0)
{
  __shared__ __align__(16) char lds[49152];
  char* const wbuf = lds;                         // 32768 B: one layer's B-tile
  const int tid = threadIdx.x;
  const int w = tid >> 6;
  const int l = tid & 63;
  const int g = l >> 4;
  const int c = l & 15;
  char* const H = lds + 32768 + w * 4096;         // per-wave 16 rows x 256 B (reused per tile)
  const long base = (long)blockIdx.x * 128 + w * 16;   // tile tt rows: base + 64*tt

  auto stage = [&](int Loff){
    #pragma unroll
    for (int it = 0; it < 8; ++it){
      int chunk = w * 8 + it;                     // 1 KiB units, 32 per block
      __builtin_amdgcn_global_load_lds((glb_u32*)(WTS + Loff + chunk * 512 + l * 8),
          (lds_u32*)(wbuf + chunk * 1024), 16, 0, 0);
    }
  };

  short8 af0[4], af1[4];
  {
    const unsigned short* xr0 = X + (base + c) * XSTR;
    const unsigned short* xr1 = X + (base + 64 + c) * XSTR;
    #pragma unroll
    for (int ks = 0; ks < 4; ++ks){
      af0[ks] = *(const short8*)(xr0 + 32 * ks + 8 * g);
      af1[ks] = *(const short8*)(xr1 + 32 * ks + 8 * g);
    }
  }

  // dual-tile MFMA block: weights read once, used twice
  auto mfma2 = [&](f32x4 (&acc0)[8], f32x4 (&acc1)[8], f32x4 blo, f32x4 bhi){
    #pragma unroll
    for (int ct = 0; ct < 8; ++ct){
      float bs = (ct < 4) ? blo[ct] : bhi[ct - 4];
      f32x4 z; z[0] = bs; z[1] = bs; z[2] = bs; z[3] = bs;
      acc0[ct] = z; acc1[ct] = z;
      const char* rowp = wbuf + ((ct * 16 + c) << 8);
      #pragma unroll
      for (int ks = 0; ks < 4; ++ks){
        short8 bf = *(const short8*)(rowp + (((4 * ks + g) ^ c) << 4));
        acc0[ct] = __builtin_amdgcn_mfma_f32_16x16x32_bf16(af0[ks], bf, acc0[ct], 0, 0, 0);
        acc1[ct] = __builtin_amdgcn_mfma_f32_16x16x32_bf16(af1[ks], bf, acc1[ct], 0, 0, 0);
      }
    }
  };

  auto gelu2 = [&](f32x2 y) -> f32x2 {
    f32x2 a = y * -2.4554673f;                    // 1.702*log2(e)
    f32x2 u;
    u[0] = __builtin_amdgcn_exp2f(a[0]);
    u[1] = __builtin_amdgcn_exp2f(a[1]);
    f32x2 d = u + 1.0f;
    f32x2 r;
    r[0] = __builtin_amdgcn_rcpf(d[0]);
    r[1] = __builtin_amdgcn_rcpf(d[1]);
    return y * r;
  };

  // LN + GELU postproc for one tile: acc -> H -> af  (f32x2 j-pairs, DPP reductions)
  auto postproc = [&](f32x4 (&acc)[8], short8 (&af)[4],
                      f32x4 glo, f32x4 ghi, f32x4 belo, f32x4 behi){
    f32x2 sA = {0.f, 0.f}, sB = {0.f, 0.f}, qA = {0.f, 0.f}, qB = {0.f, 0.f};
    #pragma unroll
    for (int ct = 0; ct < 8; ++ct){
      f32x2 xy = __builtin_shufflevector(acc[ct], acc[ct], 0, 1);
      f32x2 zw = __builtin_shufflevector(acc[ct], acc[ct], 2, 3);
      sA += xy; qA += xy * xy;
      sB += zw; qB += zw * zw;
    }
    sA[0] = rowsum16(sA[0]); sA[1] = rowsum16(sA[1]);
    sB[0] = rowsum16(sB[0]); sB[1] = rowsum16(sB[1]);
    qA[0] = rowsum16(qA[0]); qA[1] = rowsum16(qA[1]);
    qB[0] = rowsum16(qB[0]); qB[1] = rowsum16(qB[1]);
    f32x2 muA = sA * 0.0078125f, muB = sB * 0.0078125f;
    f32x2 vA = qA * 0.0078125f - muA * muA + 1e-5f;
    f32x2 vB = qB * 0.0078125f - muB * muB + 1e-5f;
    f32x2 rA, rB;
    rA[0] = rsqrtf(vA[0]); rA[1] = rsqrtf(vA[1]);
    rB[0] = rsqrtf(vB[0]); rB[1] = rsqrtf(vB[1]);
    u32x4 ov0, ov1, ov2, ov3;
    #pragma unroll
    for (int p = 0; p < 4; ++p){
      float ga0 = (p < 2) ? glo[2*p]     : ghi[2*p - 4];
      float ga1 = (p < 2) ? glo[2*p + 1] : ghi[2*p - 3];
      float be0 = (p < 2) ? belo[2*p]     : behi[2*p - 4];
      float be1 = (p < 2) ? belo[2*p + 1] : behi[2*p - 3];
      f32x2 xyE = __builtin_shufflevector(acc[2*p],   acc[2*p],   0, 1);
      f32x2 zwE = __builtin_shufflevector(acc[2*p],   acc[2*p],   2, 3);
      f32x2 xyO = __builtin_shufflevector(acc[2*p+1], acc[2*p+1], 0, 1);
      f32x2 zwO = __builtin_shufflevector(acc[2*p+1], acc[2*p+1], 2, 3);
      f32x2 AEA = rA * ga0, AEB = rB * ga0;
      f32x2 AOA = rA * ga1, AOB = rB * ga1;
      f32x2 hEA = gelu2(xyE * AEA + (be0 - muA * AEA));
      f32x2 hEB = gelu2(zwE * AEB + (be0 - muB * AEB));
      f32x2 hOA = gelu2(xyO * AOA + (be1 - muA * AOA));
      f32x2 hOB = gelu2(zwO * AOB + (be1 - muB * AOB));
      unsigned int k0, k1, k2, k3;
      asm("v_cvt_pk_bf16_f32 %0, %1, %2" : "=v"(k0) : "v"(hEA[0]), "v"(hOA[0]));
      asm("v_cvt_pk_bf16_f32 %0, %1, %2" : "=v"(k1) : "v"(hEA[1]), "v"(hOA[1]));
      asm("v_cvt_pk_bf16_f32 %0, %1, %2" : "=v"(k2) : "v"(hEB[0]), "v"(hOB[0]));
      asm("v_cvt_pk_bf16_f32 %0, %1, %2" : "=v"(k3) : "v"(hEB[1]), "v"(hOB[1]));
      ov0[p] = k0; ov1[p] = k1; ov2[p] = k2; ov3[p] = k3;
    }
    int r0 = 4 * g;
    *(u32x4*)(H + (r0 + 0) * 256 + ((c ^ (r0 + 0)) << 4)) = ov0;
    *(u32x4*)(H + (r0 + 1) * 256 + ((c ^ (r0 + 1)) << 4)) = ov1;
    *(u32x4*)(H + (r0 + 2) * 256 + ((c ^ (r0 + 2)) << 4)) = ov2;
    *(u32x4*)(H + (r0 + 3) * 256 + ((c ^ (r0 + 3)) << 4)) = ov3;
    #pragma unroll
    for (int ks = 0; ks < 4; ++ks)
      af[ks] = *(const short8*)(H + c * 256 + (((4 * ks + g) ^ c) << 4));
  };

  // rebuild e-row for chunk-local row rl: e[ct] = 20 * X[rl][c*8+ct] * dw[path,step,ct*16+c]
  auto load_e = [&](long rl) -> short8 {
    int rli = (int)rl;
    int pl = rli / 50;                      // chunk-local path (magic-mul)
    int st = rli - pl * 50;
    const float* dwr = dw + ((long)(p0 + pl) * 50 + st) * 100;
    short8 x8 = *(const short8*)(X + rl * XSTR + c * 8);
    short8 ev;
    #pragma unroll
    for (int ct = 0; ct < 8; ++ct){
      int n = ct * 16 + c;
      float wv = (n < NDIM) ? dwr[n] : 0.f;
      float e = 20.f * b2f((unsigned short)x8[ct]) * wv;
      ev[ct] = (short)f2b(e);
    }
    return ev;
  };

  // L4 epilogue for one tile (e rows preloaded), f32x2 sigmoid + DPP reduce
  auto epilogue = [&](f32x4 (&acc)[8], short8 (&ep)[4], long rbase){
    f32x2 pgA = {0.f, 0.f}, pgB = {0.f, 0.f};
    #pragma unroll
    for (int ct = 0; ct < 8; ++ct){
      f32x2 xy = __builtin_shufflevector(acc[ct], acc[ct], 0, 1);
      f32x2 zw = __builtin_shufflevector(acc[ct], acc[ct], 2, 3);
      f32x2 aA = xy * -1.4426950f, aB = zw * -1.4426950f;
      f32x2 u, d, r;
      u[0] = __builtin_amdgcn_exp2f(aA[0]); u[1] = __builtin_amdgcn_exp2f(aA[1]);
      d = u + 1.f;
      r[0] = __builtin_amdgcn_rcpf(d[0]); r[1] = __builtin_amdgcn_rcpf(d[1]);
      f32x2 eA = { b2f((unsigned short)ep[0][ct]), b2f((unsigned short)ep[1][ct]) };
      pgA += r * eA;
      u[0] = __builtin_amdgcn_exp2f(aB[0]); u[1] = __builtin_amdgcn_exp2f(aB[1]);
      d = u + 1.f;
      r[0] = __builtin_amdgcn_rcpf(d[0]); r[1] = __builtin_amdgcn_rcpf(d[1]);
      f32x2 eB = { b2f((unsigned short)ep[2][ct]), b2f((unsigned short)ep[3][ct]) };
      pgB += r * eB;
    }
    pgA[0] = rowsum16(pgA[0]); pgA[1] = rowsum16(pgA[1]);
    pgB[0] = rowsum16(pgB[0]); pgB[1] = rowsum16(pgB[1]);
    if (c == 0){
      cbuf[row0 + rbase + 4 * g + 0] = pgA[0];
      cbuf[row0 + rbase + 4 * g + 1] = pgA[1];
      cbuf[row0 + rbase + 4 * g + 2] = pgB[0];
      cbuf[row0 + rbase + 4 * g + 3] = pgB[1];
    }
  };

  stage(0);
  __syncthreads();

  #pragma unroll
  for (int L = 0; L < 3; ++L){
    const float* pp = PPAR + L * 384 + c * 8;
    f32x4 blo  = *(const f32x4*)pp,         bhi  = *(const f32x4*)(pp + 4);
    f32x4 acc0[8], acc1[8];
    mfma2(acc0, acc1, blo, bhi);
    f32x4 glo  = *(const f32x4*)(pp + 128), ghi  = *(const f32x4*)(pp + 132);
    f32x4 belo = *(const f32x4*)(pp + 256), behi = *(const f32x4*)(pp + 260);
    __syncthreads();                       // all waves done reading wbuf
    stage((L + 1) * 16384);                // async DMA next layer, overlaps postproc
    postproc(acc0, af0, glo, ghi, belo, behi);
    postproc(acc1, af1, glo, ghi, belo, behi);
    __syncthreads();                       // drains vmcnt -> wbuf ready
  }

  {
    const float* pp = PPAR + 3 * 384 + c * 8;
    f32x4 blo = *(const f32x4*)pp, bhi = *(const f32x4*)(pp + 4);
    short8 ep0[4], ep1[4];
    #pragma unroll
    for (int j = 0; j < 4; ++j){
      ep0[j] = load_e(base + 4 * g + j);       // loads issued before mfma2,
      ep1[j] = load_e(base + 64 + 4 * g + j);  // consumed after -> latency hidden
    }
    f32x4 acc0[8], acc1[8];
    mfma2(acc0, acc1, blo, bhi);
    epilogue(acc0, ep0, base);
    epilogue(acc1, ep1, base + 64);
  }
}

// ---------------- Phase C: affine fold -> Y ----------------
__global__ __launch_bounds__(256) void phaseC(const float* __restrict__ cbuf,
                                              const float* __restrict__ Y0,
                                              float* __restrict__ Yout)
{
  int b = blockIdx.x * 256 + threadIdx.x;
  if (b >= NPATH) return;
  const float kk = 1.0f + 0.05f * (1.0f / 50.0f);   // 1 + R*DT
  float y = Y0[0];
  const float* cb = cbuf + (long)b * NSTEP;
  #pragma unroll 10
  for (int i = 0; i < NSTEP; ++i) y = y * kk + cb[i];
  Yout[b] = y;
}

extern "C" void kernel_launch(void* const* d_in, const int* in_sizes, int n_in,
                              void* d_out, int out_size, void* d_ws, size_t ws_size,
                              hipStream_t stream)
{
  const float* dw  = (const float*)d_in[0];
  const float* tg  = (const float*)d_in[1];
  const float* W1  = (const float*)d_in[2];
  const float* b1  = (const float*)d_in[3];
  const float* g1  = (const float*)d_in[4];
  const float* be1 = (const float*)d_in[5];
  const float* W2  = (const float*)d_in[6];
  const float* b2  = (const float*)d_in[7];
  const float* g2  = (const float*)d_in[8];
  const float* be2 = (const float*)d_in[9];
  const float* W3  = (const float*)d_in[10];
  const float* b3  = (const float*)d_in[11];
  const float* g3  = (const float*)d_in[12];
  const float* be3 = (const float*)d_in[13];
  const float* W4  = (const float*)d_in[14];
  const float* b4  = (const float*)d_in[15];
  const float* Y0  = (const float*)d_in[16];
  float* out = (float*)d_out;               // [0,8192): Y ; [8192,8192+819200): S

  char* ws = (char*)d_ws;
  unsigned short* WTS = (unsigned short*)ws;        // 131072 B
  float* PPAR = (float*)(ws + 131072);              // 1536 * 4 B
  float* cbuf = (float*)(ws + 137344);              // 409600 * 4 B
  char* chunk = ws + 1775744;                       // X chunk region (16B aligned)

  prep_all<<<262, 256, 0, stream>>>(W1, W2, W3, W4,
      b1, g1, be1, b2, g2, be2, b3, g3, be3, b4, WTS, PPAR);

  long avail = (long)ws_size - 1775744L;
  long pc = (avail > 0) ? (avail / 12800L) : 0;     // per-path: 12800 B (X only)
  if (pc > 4096) pc = 4096;                          // chunk-dw (82MB) + X (52MB) L3-fit
  pc -= pc % 128;                                   // rows multiple of 128
  if (pc < 128) pc = 128;

  for (long p0 = 0; p0 < 8192; p0 += pc){
    long np = 8192 - p0; if (np > pc) np = pc;
    unsigned short* Xc = (unsigned short*)chunk;
    phaseA<<<(int)(np / 4), 256, 0, stream>>>(dw, tg, Xc, out + 8192, (int)p0);
    long nrows = np * 50L;
    phaseB<<<(int)(nrows / 128), 256, 0, stream>>>(Xc, dw, WTS, PPAR, cbuf,
        p0 * 50L, (int)p0);
  }
  phaseC<<<32, 256, 0, stream>>>(cbuf, Y0, out);
}

// Round 16
// 229.787 us; speedup vs baseline: 1.1155x; 1.1155x over previous
//
#include <hip/hip_runtime.h>
#include <hip/hip_bf16.h>
#include <cstdint>
#include <cstddef>

typedef __attribute__((ext_vector_type(8))) short short8;
typedef __attribute__((ext_vector_type(4))) float f32x4;
typedef __attribute__((ext_vector_type(2))) float f32x2;
typedef __attribute__((ext_vector_type(4))) unsigned int u32x4;

#define NDIM 100
#define NSTEP 50
#define NPATH 8192
#define XSTR 128   // X row: position i holds physical dim k(i)=(i&7)*16+(i>>3); dim100=t at pos38
#define ESTR 128   // E row: same permutation; e = 0.2*S*w, zero-padded

typedef const __attribute__((address_space(1))) unsigned int glb_u32;
typedef __attribute__((address_space(3))) unsigned int lds_u32;

__device__ __forceinline__ unsigned short f2b(float f){
  unsigned int u = __float_as_uint(f);
  u += 0x7fffu + ((u >> 16) & 1u);          // RNE
  return (unsigned short)(u >> 16);
}
__device__ __forceinline__ float b2f(unsigned short h){
  return __uint_as_float(((unsigned int)h) << 16);
}

// 16-lane (DPP row) full reduction via row_ror adds — VALU pipe, no LDS ops.
template<int CTRL>
__device__ __forceinline__ float dpp_add(float x){
  int t = __builtin_amdgcn_update_dpp(0, __float_as_int(x), CTRL, 0xF, 0xF, true);
  return x + __int_as_float(t);
}
__device__ __forceinline__ float rowsum16(float x){
  x = dpp_add<0x128>(x);   // row_ror:8
  x = dpp_add<0x124>(x);   // row_ror:4
  x = dpp_add<0x122>(x);   // row_ror:2
  x = dpp_add<0x121>(x);   // row_ror:1
  return x;
}

// ---------------- combined prep: weights (swizzled LDS image) + params ----------------
__global__ __launch_bounds__(256) void prep_all(
    const float* __restrict__ W1, const float* __restrict__ W2,
    const float* __restrict__ W3, const float* __restrict__ W4,
    const float* __restrict__ b1, const float* __restrict__ g1, const float* __restrict__ be1,
    const float* __restrict__ b2, const float* __restrict__ g2, const float* __restrict__ be2,
    const float* __restrict__ b3, const float* __restrict__ g3, const float* __restrict__ be3,
    const float* __restrict__ b4,
    unsigned short* __restrict__ WTS, float* __restrict__ PPAR)
{
  if (blockIdx.x < 256){
    int idx = blockIdx.x * 256 + threadIdx.x;   // 65536 weight elems
    int j = idx & 7;
    int s = (idx >> 3) & 15;
    int n = (idx >> 7) & 127;
    int L = idx >> 14;
    int lc = s ^ (n & 15);
    int k  = j * 16 + lc;                       // physical k
    float v;
    if (L == 0)      v = (k <= NDIM) ? W1[k * 128 + n] : 0.f;
    else if (L == 1) v = W2[k * 128 + n];
    else if (L == 2) v = W3[k * 128 + n];
    else             v = (n < NDIM) ? W4[k * NDIM + n] : 0.f;
    WTS[idx] = f2b(v);
    return;
  }
  int idx = (blockIdx.x - 256) * 256 + threadIdx.x;   // 1536 param elems
  if (idx >= 1536) return;
  int ct = idx & 7;
  int c  = (idx >> 3) & 15;
  int p  = (idx >> 7) % 3;
  int L  = idx / 384;
  int col = ct * 16 + c;
  const float* v;
  if (L == 0)      v = (p == 0) ? b1 : (p == 1) ? g1 : be1;
  else if (L == 1) v = (p == 0) ? b2 : (p == 1) ? g2 : be2;
  else if (L == 2) v = (p == 0) ? b3 : (p == 1) ? g3 : be3;
  else             v = b4;
  float val;
  if (L == 3) val = (p == 0 && col < NDIM) ? b4[col] : 0.f;
  else        val = v[col];
  PPAR[idx] = val;
}

// ---------------- Phase A: S-chain scan -> permuted X / E rows + final S ----------------
// FULL rows written (pads zero) — R14 lesson: holed wave-stores halve write BW.
__global__ __launch_bounds__(256) void phaseA(
    const float* __restrict__ dw, const float* __restrict__ tg,
    unsigned short* __restrict__ X, unsigned short* __restrict__ E,
    float* __restrict__ Sout, int path0)
{
  const int pb = threadIdx.x >> 6;
  const int t  = threadIdx.x & 63;
  const int bl = blockIdx.x * 4 + pb;          // chunk-local path
  const int b  = path0 + bl;
  const int d0 = (t & 7) * 16 + (t >> 3);
  const int d1 = d0 + 8;
  float s0 = 100.f, s1 = 100.f;
  const float* dwb = dw + (long)b * NSTEP * NDIM;
  const float* tgb = tg + (long)b * NSTEP;
  unsigned short* Xb = X + (long)bl * NSTEP * XSTR;
  unsigned short* Eb = E + (long)bl * NSTEP * ESTR;
  for (int i = 0; i < NSTEP; ++i){
    float tv = tgb[i];
    float w0 = (d0 < NDIM) ? dwb[i * NDIM + d0] : 0.f;
    float w1 = (d1 < NDIM) ? dwb[i * NDIM + d1] : 0.f;
    unsigned short* Xr = Xb + i * XSTR;
    unsigned short* Er = Eb + i * ESTR;
    Xr[t]      = (d0 < NDIM) ? f2b(s0 * 0.01f) : ((d0 == NDIM) ? f2b(tv) : (unsigned short)0);
    Xr[t + 64] = (d1 < NDIM) ? f2b(s1 * 0.01f) : (unsigned short)0;   // d1 is never ==100
    Er[t]      = (d0 < NDIM) ? f2b(0.2f * s0 * w0) : (unsigned short)0;
    Er[t + 64] = (d1 < NDIM) ? f2b(0.2f * s1 * w1) : (unsigned short)0;
    s0 = fmaf(s0, 0.001f + 0.2f * w0, s0);
    s1 = fmaf(s1, 0.001f + 0.2f * w1, s1);
  }
  if (d0 < NDIM) Sout[(long)b * NDIM + d0] = s0;
  if (d1 < NDIM) Sout[(long)b * NDIM + d1] = s1;
}

// ---------------- Phase B: fused 4-layer MLP, 3 row-tiles/wave (192 rows/block) ----------------
// R12 postproc/epilogue verbatim; 3 tiles amortize barriers + weight ds_reads + stage
// DMA per row by 1/3. Pad rows (beyond nrows) compute garbage, writes guarded.
__global__ __launch_bounds__(256, 3) void phaseB(
    const unsigned short* __restrict__ X,
    const unsigned short* __restrict__ E,
    const unsigned short* __restrict__ WTS,
    const float* __restrict__ PPAR,
    float* __restrict__ cbuf, long row0, long nrows)
{
  __shared__ __align__(16) char lds[49152];
  char* const wbuf = lds;                         // 32768 B: one layer's B-tile
  const int tid = threadIdx.x;
  const int w = tid >> 6;
  const int l = tid & 63;
  const int g = l >> 4;
  const int c = l & 15;
  char* const H = lds + 32768 + w * 4096;         // per-wave 16 rows x 256 B (reused per tile)
  const long base = (long)blockIdx.x * 192 + w * 16;   // tile tt rows: base + 64*tt

  auto stage = [&](int Loff){
    #pragma unroll
    for (int it = 0; it < 8; ++it){
      int chunk = w * 8 + it;                     // 1 KiB units, 32 per block
      __builtin_amdgcn_global_load_lds((glb_u32*)(WTS + Loff + chunk * 512 + l * 8),
          (lds_u32*)(wbuf + chunk * 1024), 16, 0, 0);
    }
  };

  short8 af0[4], af1[4], af2[4];
  {
    const unsigned short* xr0 = X + (base + c) * XSTR;
    const unsigned short* xr1 = X + (base + 64 + c) * XSTR;
    const unsigned short* xr2 = X + (base + 128 + c) * XSTR;
    #pragma unroll
    for (int ks = 0; ks < 4; ++ks){
      af0[ks] = *(const short8*)(xr0 + 32 * ks + 8 * g);
      af1[ks] = *(const short8*)(xr1 + 32 * ks + 8 * g);
      af2[ks] = *(const short8*)(xr2 + 32 * ks + 8 * g);
    }
  }

  // triple-tile MFMA block: weights read once, used three times
  auto mfma3 = [&](f32x4 (&acc0)[8], f32x4 (&acc1)[8], f32x4 (&acc2)[8],
                   f32x4 blo, f32x4 bhi){
    #pragma unroll
    for (int ct = 0; ct < 8; ++ct){
      float bs = (ct < 4) ? blo[ct] : bhi[ct - 4];
      f32x4 z; z[0] = bs; z[1] = bs; z[2] = bs; z[3] = bs;
      acc0[ct] = z; acc1[ct] = z; acc2[ct] = z;
      const char* rowp = wbuf + ((ct * 16 + c) << 8);
      #pragma unroll
      for (int ks = 0; ks < 4; ++ks){
        short8 bf = *(const short8*)(rowp + (((4 * ks + g) ^ c) << 4));
        acc0[ct] = __builtin_amdgcn_mfma_f32_16x16x32_bf16(af0[ks], bf, acc0[ct], 0, 0, 0);
        acc1[ct] = __builtin_amdgcn_mfma_f32_16x16x32_bf16(af1[ks], bf, acc1[ct], 0, 0, 0);
        acc2[ct] = __builtin_amdgcn_mfma_f32_16x16x32_bf16(af2[ks], bf, acc2[ct], 0, 0, 0);
      }
    }
  };

  auto gelu2 = [&](f32x2 y) -> f32x2 {
    f32x2 a = y * -2.4554673f;                    // 1.702*log2(e)
    f32x2 u;
    u[0] = __builtin_amdgcn_exp2f(a[0]);
    u[1] = __builtin_amdgcn_exp2f(a[1]);
    f32x2 d = u + 1.0f;
    f32x2 r;
    r[0] = __builtin_amdgcn_rcpf(d[0]);
    r[1] = __builtin_amdgcn_rcpf(d[1]);
    return y * r;
  };

  // LN + GELU postproc for one tile: acc -> H -> af  (f32x2 j-pairs, DPP reductions)
  auto postproc = [&](f32x4 (&acc)[8], short8 (&af)[4],
                      f32x4 glo, f32x4 ghi, f32x4 belo, f32x4 behi){
    f32x2 sA = {0.f, 0.f}, sB = {0.f, 0.f}, qA = {0.f, 0.f}, qB = {0.f, 0.f};
    #pragma unroll
    for (int ct = 0; ct < 8; ++ct){
      f32x2 xy = __builtin_shufflevector(acc[ct], acc[ct], 0, 1);
      f32x2 zw = __builtin_shufflevector(acc[ct], acc[ct], 2, 3);
      sA += xy; qA += xy * xy;
      sB += zw; qB += zw * zw;
    }
    sA[0] = rowsum16(sA[0]); sA[1] = rowsum16(sA[1]);
    sB[0] = rowsum16(sB[0]); sB[1] = rowsum16(sB[1]);
    qA[0] = rowsum16(qA[0]); qA[1] = rowsum16(qA[1]);
    qB[0] = rowsum16(qB[0]); qB[1] = rowsum16(qB[1]);
    f32x2 muA = sA * 0.0078125f, muB = sB * 0.0078125f;
    f32x2 vA = qA * 0.0078125f - muA * muA + 1e-5f;
    f32x2 vB = qB * 0.0078125f - muB * muB + 1e-5f;
    f32x2 rA, rB;
    rA[0] = rsqrtf(vA[0]); rA[1] = rsqrtf(vA[1]);
    rB[0] = rsqrtf(vB[0]); rB[1] = rsqrtf(vB[1]);
    u32x4 ov0, ov1, ov2, ov3;
    #pragma unroll
    for (int p = 0; p < 4; ++p){
      float ga0 = (p < 2) ? glo[2*p]     : ghi[2*p - 4];
      float ga1 = (p < 2) ? glo[2*p + 1] : ghi[2*p - 3];
      float be0 = (p < 2) ? belo[2*p]     : behi[2*p - 4];
      float be1 = (p < 2) ? belo[2*p + 1] : behi[2*p - 3];
      f32x2 xyE = __builtin_shufflevector(acc[2*p],   acc[2*p],   0, 1);
      f32x2 zwE = __builtin_shufflevector(acc[2*p],   acc[2*p],   2, 3);
      f32x2 xyO = __builtin_shufflevector(acc[2*p+1], acc[2*p+1], 0, 1);
      f32x2 zwO = __builtin_shufflevector(acc[2*p+1], acc[2*p+1], 2, 3);
      f32x2 AEA = rA * ga0, AEB = rB * ga0;
      f32x2 AOA = rA * ga1, AOB = rB * ga1;
      f32x2 hEA = gelu2(xyE * AEA + (be0 - muA * AEA));
      f32x2 hEB = gelu2(zwE * AEB + (be0 - muB * AEB));
      f32x2 hOA = gelu2(xyO * AOA + (be1 - muA * AOA));
      f32x2 hOB = gelu2(zwO * AOB + (be1 - muB * AOB));
      unsigned int k0, k1, k2, k3;
      asm("v_cvt_pk_bf16_f32 %0, %1, %2" : "=v"(k0) : "v"(hEA[0]), "v"(hOA[0]));
      asm("v_cvt_pk_bf16_f32 %0, %1, %2" : "=v"(k1) : "v"(hEA[1]), "v"(hOA[1]));
      asm("v_cvt_pk_bf16_f32 %0, %1, %2" : "=v"(k2) : "v"(hEB[0]), "v"(hOB[0]));
      asm("v_cvt_pk_bf16_f32 %0, %1, %2" : "=v"(k3) : "v"(hEB[1]), "v"(hOB[1]));
      ov0[p] = k0; ov1[p] = k1; ov2[p] = k2; ov3[p] = k3;
    }
    int r0 = 4 * g;
    *(u32x4*)(H + (r0 + 0) * 256 + ((c ^ (r0 + 0)) << 4)) = ov0;
    *(u32x4*)(H + (r0 + 1) * 256 + ((c ^ (r0 + 1)) << 4)) = ov1;
    *(u32x4*)(H + (r0 + 2) * 256 + ((c ^ (r0 + 2)) << 4)) = ov2;
    *(u32x4*)(H + (r0 + 3) * 256 + ((c ^ (r0 + 3)) << 4)) = ov3;
    #pragma unroll
    for (int ks = 0; ks < 4; ++ks)
      af[ks] = *(const short8*)(H + c * 256 + (((4 * ks + g) ^ c) << 4));
  };

  // L4 epilogue for one tile; E rows loaded here (per-tile, caps reg pressure)
  auto epilogue = [&](f32x4 (&acc)[8], long rbase){
    short8 ep[4];
    #pragma unroll
    for (int j = 0; j < 4; ++j)
      ep[j] = *(const short8*)(E + (rbase + 4 * g + j) * ESTR + c * 8);
    f32x2 pgA = {0.f, 0.f}, pgB = {0.f, 0.f};
    #pragma unroll
    for (int ct = 0; ct < 8; ++ct){
      f32x2 xy = __builtin_shufflevector(acc[ct], acc[ct], 0, 1);
      f32x2 zw = __builtin_shufflevector(acc[ct], acc[ct], 2, 3);
      f32x2 aA = xy * -1.4426950f, aB = zw * -1.4426950f;
      f32x2 u, d, r;
      u[0] = __builtin_amdgcn_exp2f(aA[0]); u[1] = __builtin_amdgcn_exp2f(aA[1]);
      d = u + 1.f;
      r[0] = __builtin_amdgcn_rcpf(d[0]); r[1] = __builtin_amdgcn_rcpf(d[1]);
      f32x2 eA = { b2f((unsigned short)ep[0][ct]), b2f((unsigned short)ep[1][ct]) };
      pgA += r * eA;
      u[0] = __builtin_amdgcn_exp2f(aB[0]); u[1] = __builtin_amdgcn_exp2f(aB[1]);
      d = u + 1.f;
      r[0] = __builtin_amdgcn_rcpf(d[0]); r[1] = __builtin_amdgcn_rcpf(d[1]);
      f32x2 eB = { b2f((unsigned short)ep[2][ct]), b2f((unsigned short)ep[3][ct]) };
      pgB += r * eB;
    }
    pgA[0] = rowsum16(pgA[0]); pgA[1] = rowsum16(pgA[1]);
    pgB[0] = rowsum16(pgB[0]); pgB[1] = rowsum16(pgB[1]);
    if (c == 0){
      long r = rbase + 4 * g;
      if (r + 0 < nrows) cbuf[row0 + r + 0] = pgA[0];
      if (r + 1 < nrows) cbuf[row0 + r + 1] = pgA[1];
      if (r + 2 < nrows) cbuf[row0 + r + 2] = pgB[0];
      if (r + 3 < nrows) cbuf[row0 + r + 3] = pgB[1];
    }
  };

  stage(0);
  __syncthreads();

  #pragma unroll
  for (int L = 0; L < 3; ++L){
    const float* pp = PPAR + L * 384 + c * 8;
    f32x4 blo  = *(const f32x4*)pp,         bhi  = *(const f32x4*)(pp + 4);
    f32x4 acc0[8], acc1[8], acc2[8];
    mfma3(acc0, acc1, acc2, blo, bhi);
    f32x4 glo  = *(const f32x4*)(pp + 128), ghi  = *(const f32x4*)(pp + 132);
    f32x4 belo = *(const f32x4*)(pp + 256), behi = *(const f32x4*)(pp + 260);
    __syncthreads();                       // all waves done reading wbuf
    stage((L + 1) * 16384);                // async DMA next layer, overlaps postproc
    postproc(acc0, af0, glo, ghi, belo, behi);
    postproc(acc1, af1, glo, ghi, belo, behi);
    postproc(acc2, af2, glo, ghi, belo, behi);
    __syncthreads();                       // drains vmcnt -> wbuf ready
  }

  {
    const float* pp = PPAR + 3 * 384 + c * 8;
    f32x4 blo = *(const f32x4*)pp, bhi = *(const f32x4*)(pp + 4);
    f32x4 acc0[8], acc1[8], acc2[8];
    mfma3(acc0, acc1, acc2, blo, bhi);
    epilogue(acc0, base);
    epilogue(acc1, base + 64);
    epilogue(acc2, base + 128);
  }
}

// ---------------- Phase C: affine fold -> Y ----------------
__global__ __launch_bounds__(256) void phaseC(const float* __restrict__ cbuf,
                                              const float* __restrict__ Y0,
                                              float* __restrict__ Yout)
{
  int b = blockIdx.x * 256 + threadIdx.x;
  if (b >= NPATH) return;
  const float kk = 1.0f + 0.05f * (1.0f / 50.0f);   // 1 + R*DT
  float y = Y0[0];
  const float* cb = cbuf + (long)b * NSTEP;
  #pragma unroll 10
  for (int i = 0; i < NSTEP; ++i) y = y * kk + cb[i];
  Yout[b] = y;
}

extern "C" void kernel_launch(void* const* d_in, const int* in_sizes, int n_in,
                              void* d_out, int out_size, void* d_ws, size_t ws_size,
                              hipStream_t stream)
{
  const float* dw  = (const float*)d_in[0];
  const float* tg  = (const float*)d_in[1];
  const float* W1  = (const float*)d_in[2];
  const float* b1  = (const float*)d_in[3];
  const float* g1  = (const float*)d_in[4];
  const float* be1 = (const float*)d_in[5];
  const float* W2  = (const float*)d_in[6];
  const float* b2  = (const float*)d_in[7];
  const float* g2  = (const float*)d_in[8];
  const float* be2 = (const float*)d_in[9];
  const float* W3  = (const float*)d_in[10];
  const float* b3  = (const float*)d_in[11];
  const float* g3  = (const float*)d_in[12];
  const float* be3 = (const float*)d_in[13];
  const float* W4  = (const float*)d_in[14];
  const float* b4  = (const float*)d_in[15];
  const float* Y0  = (const float*)d_in[16];
  float* out = (float*)d_out;               // [0,8192): Y ; [8192,8192+819200): S

  char* ws = (char*)d_ws;
  unsigned short* WTS = (unsigned short*)ws;        // 131072 B
  float* PPAR = (float*)(ws + 131072);              // 1536 * 4 B
  float* cbuf = (float*)(ws + 137344);              // 409600 * 4 B
  char* chunk = ws + 1775744;                       // X/E chunk region (16B aligned)

  prep_all<<<262, 256, 0, stream>>>(W1, W2, W3, W4,
      b1, g1, be1, b2, g2, be2, b3, g3, be3, b4, WTS, PPAR);

  long avail = (long)ws_size - 1775744L - 262144L;  // 256KB margin for 192-row padding
  long pc = (avail > 0) ? (avail / 25600L) : 0;     // per-path: 12800 (X) + 12800 (E) B
  if (pc > 8192) pc = 8192;
  pc -= pc % 128;                                   // paths multiple of 128
  if (pc < 128) pc = 128;

  for (long p0 = 0; p0 < 8192; p0 += pc){
    long np = 8192 - p0; if (np > pc) np = pc;
    long nrows = np * 50L;
    long padRows = ((nrows + 191L) / 192L) * 192L;
    unsigned short* Xc = (unsigned short*)chunk;
    unsigned short* Ec = Xc + padRows * XSTR;
    phaseA<<<(int)(np / 4), 256, 0, stream>>>(dw, tg, Xc, Ec, out + 8192, (int)p0);
    phaseB<<<(int)(padRows / 192), 256, 0, stream>>>(Xc, Ec, WTS, PPAR, cbuf,
        p0 * 50L, nrows);
  }
  phaseC<<<32, 256, 0, stream>>>(cbuf, Y0, out);
}

// Round 17
// 199.645 us; speedup vs baseline: 1.2839x; 1.1510x over previous
//
#include <hip/hip_runtime.h>
#include <hip/hip_bf16.h>
#include <cstdint>
#include <cstddef>

typedef __attribute__((ext_vector_type(8))) short short8;
typedef __attribute__((ext_vector_type(4))) float f32x4;
typedef __attribute__((ext_vector_type(2))) float f32x2;
typedef __attribute__((ext_vector_type(4))) unsigned int u32x4;

#define NDIM 100
#define NSTEP 50
#define NPATH 8192
#define XSTR 128   // X row: position i holds physical dim k(i)=(i&7)*16+(i>>3); dim100=t at pos38
#define ESTR 128   // E row: same permutation; e = 0.2*S*w, zero-padded

typedef const __attribute__((address_space(1))) unsigned int glb_u32;
typedef __attribute__((address_space(3))) unsigned int lds_u32;

__device__ __forceinline__ unsigned short f2b(float f){
  unsigned int u = __float_as_uint(f);
  u += 0x7fffu + ((u >> 16) & 1u);          // RNE
  return (unsigned short)(u >> 16);
}
__device__ __forceinline__ float b2f(unsigned short h){
  return __uint_as_float(((unsigned int)h) << 16);
}

// 16-lane (DPP row) full reduction via row_ror adds — VALU pipe, no LDS ops.
template<int CTRL>
__device__ __forceinline__ float dpp_add(float x){
  int t = __builtin_amdgcn_update_dpp(0, __float_as_int(x), CTRL, 0xF, 0xF, true);
  return x + __int_as_float(t);
}
__device__ __forceinline__ float rowsum16(float x){
  x = dpp_add<0x128>(x);   // row_ror:8
  x = dpp_add<0x124>(x);   // row_ror:4
  x = dpp_add<0x122>(x);   // row_ror:2
  x = dpp_add<0x121>(x);   // row_ror:1
  return x;                // every lane in the 16-lane row holds the full sum
}

// ---------------- combined prep: weights (swizzled LDS image) + params ----------------
// Blocks [0,256): WTS elem ((L*128+n)*16+s)*8+j = W_L[kphys][n], lc=s^(n&15), kphys=j*16+lc.
// Blocks [256,262): PPAR[L][p][c][ct] (p: 0=bias 1=gamma 2=beta; L=3 only bias, padded).
__global__ __launch_bounds__(256) void prep_all(
    const float* __restrict__ W1, const float* __restrict__ W2,
    const float* __restrict__ W3, const float* __restrict__ W4,
    const float* __restrict__ b1, const float* __restrict__ g1, const float* __restrict__ be1,
    const float* __restrict__ b2, const float* __restrict__ g2, const float* __restrict__ be2,
    const float* __restrict__ b3, const float* __restrict__ g3, const float* __restrict__ be3,
    const float* __restrict__ b4,
    unsigned short* __restrict__ WTS, float* __restrict__ PPAR)
{
  if (blockIdx.x < 256){
    int idx = blockIdx.x * 256 + threadIdx.x;   // 65536 weight elems
    int j = idx & 7;
    int s = (idx >> 3) & 15;
    int n = (idx >> 7) & 127;
    int L = idx >> 14;
    int lc = s ^ (n & 15);
    int k  = j * 16 + lc;                       // physical k
    float v;
    if (L == 0)      v = (k <= NDIM) ? W1[k * 128 + n] : 0.f;
    else if (L == 1) v = W2[k * 128 + n];
    else if (L == 2) v = W3[k * 128 + n];
    else             v = (n < NDIM) ? W4[k * NDIM + n] : 0.f;
    WTS[idx] = f2b(v);
    return;
  }
  int idx = (blockIdx.x - 256) * 256 + threadIdx.x;   // 1536 param elems
  if (idx >= 1536) return;
  int ct = idx & 7;
  int c  = (idx >> 3) & 15;
  int p  = (idx >> 7) % 3;
  int L  = idx / 384;
  int col = ct * 16 + c;
  const float* v;
  if (L == 0)      v = (p == 0) ? b1 : (p == 1) ? g1 : be1;
  else if (L == 1) v = (p == 0) ? b2 : (p == 1) ? g2 : be2;
  else if (L == 2) v = (p == 0) ? b3 : (p == 1) ? g3 : be3;
  else             v = b4;
  float val;
  if (L == 3) val = (p == 0 && col < NDIM) ? b4[col] : 0.f;
  else        val = v[col];
  PPAR[idx] = val;
}

// ---------------- Phase A: S-chain scan -> permuted X / E rows + final S ----------------
// FULL rows written (pads zero) — R14 lesson: holed wave-stores halve write BW.
__global__ __launch_bounds__(256) void phaseA(
    const float* __restrict__ dw, const float* __restrict__ tg,
    unsigned short* __restrict__ X, unsigned short* __restrict__ E,
    float* __restrict__ Sout, int path0)
{
  const int pb = threadIdx.x >> 6;
  const int t  = threadIdx.x & 63;
  const int bl = blockIdx.x * 4 + pb;          // chunk-local path
  const int b  = path0 + bl;
  const int d0 = (t & 7) * 16 + (t >> 3);
  const int d1 = d0 + 8;
  float s0 = 100.f, s1 = 100.f;
  const float* dwb = dw + (long)b * NSTEP * NDIM;
  const float* tgb = tg + (long)b * NSTEP;
  unsigned short* Xb = X + (long)bl * NSTEP * XSTR;
  unsigned short* Eb = E + (long)bl * NSTEP * ESTR;
  for (int i = 0; i < NSTEP; ++i){
    float tv = tgb[i];
    float w0 = (d0 < NDIM) ? dwb[i * NDIM + d0] : 0.f;
    float w1 = (d1 < NDIM) ? dwb[i * NDIM + d1] : 0.f;
    unsigned short* Xr = Xb + i * XSTR;
    unsigned short* Er = Eb + i * ESTR;
    Xr[t]      = (d0 < NDIM) ? f2b(s0 * 0.01f) : ((d0 == NDIM) ? f2b(tv) : (unsigned short)0);
    Xr[t + 64] = (d1 < NDIM) ? f2b(s1 * 0.01f) : (unsigned short)0;   // d1 is never ==100
    Er[t]      = (d0 < NDIM) ? f2b(0.2f * s0 * w0) : (unsigned short)0;
    Er[t + 64] = (d1 < NDIM) ? f2b(0.2f * s1 * w1) : (unsigned short)0;
    s0 = fmaf(s0, 0.001f + 0.2f * w0, s0);
    s1 = fmaf(s1, 0.001f + 0.2f * w1, s1);
  }
  if (d0 < NDIM) Sout[(long)b * NDIM + d0] = s0;
  if (d1 < NDIM) Sout[(long)b * NDIM + d1] = s1;
}

// ---------------- Phase B: fused 4-layer MLP, 2 row-tiles/wave (128 rows/block) ----------------
// R12 body verbatim — best measured (121µs): DPP reductions + f32x2 j-pair packing,
// 49KB LDS, (256,3), conflict-free swizzled weight/H b128 access, stage-overlap.
// 2 tiles/wave is the register-budget sweet spot: 3 tiles spills (R16), 1 tile
// under-amortizes (R4). Do not perturb without checking WRITE_SIZE for scratch.
__global__ __launch_bounds__(256, 3) void phaseB(
    const unsigned short* __restrict__ X,
    const unsigned short* __restrict__ E,
    const unsigned short* __restrict__ WTS,
    const float* __restrict__ PPAR,
    float* __restrict__ cbuf, long row0)
{
  __shared__ __align__(16) char lds[49152];
  char* const wbuf = lds;                         // 32768 B: one layer's B-tile
  const int tid = threadIdx.x;
  const int w = tid >> 6;
  const int l = tid & 63;
  const int g = l >> 4;
  const int c = l & 15;
  char* const H = lds + 32768 + w * 4096;         // per-wave 16 rows x 256 B (reused per tile)
  const long base = (long)blockIdx.x * 128 + w * 16;   // tile tt rows: base + 64*tt

  auto stage = [&](int Loff){
    #pragma unroll
    for (int it = 0; it < 8; ++it){
      int chunk = w * 8 + it;                     // 1 KiB units, 32 per block
      __builtin_amdgcn_global_load_lds((glb_u32*)(WTS + Loff + chunk * 512 + l * 8),
          (lds_u32*)(wbuf + chunk * 1024), 16, 0, 0);
    }
  };

  short8 af0[4], af1[4];
  {
    const unsigned short* xr0 = X + (base + c) * XSTR;
    const unsigned short* xr1 = X + (base + 64 + c) * XSTR;
    #pragma unroll
    for (int ks = 0; ks < 4; ++ks){
      af0[ks] = *(const short8*)(xr0 + 32 * ks + 8 * g);
      af1[ks] = *(const short8*)(xr1 + 32 * ks + 8 * g);
    }
  }

  // dual-tile MFMA block: weights read once, used twice
  auto mfma2 = [&](f32x4 (&acc0)[8], f32x4 (&acc1)[8], f32x4 blo, f32x4 bhi){
    #pragma unroll
    for (int ct = 0; ct < 8; ++ct){
      float bs = (ct < 4) ? blo[ct] : bhi[ct - 4];
      f32x4 z; z[0] = bs; z[1] = bs; z[2] = bs; z[3] = bs;
      acc0[ct] = z; acc1[ct] = z;
      const char* rowp = wbuf + ((ct * 16 + c) << 8);
      #pragma unroll
      for (int ks = 0; ks < 4; ++ks){
        short8 bf = *(const short8*)(rowp + (((4 * ks + g) ^ c) << 4));
        acc0[ct] = __builtin_amdgcn_mfma_f32_16x16x32_bf16(af0[ks], bf, acc0[ct], 0, 0, 0);
        acc1[ct] = __builtin_amdgcn_mfma_f32_16x16x32_bf16(af1[ks], bf, acc1[ct], 0, 0, 0);
      }
    }
  };

  auto gelu2 = [&](f32x2 y) -> f32x2 {
    f32x2 a = y * -2.4554673f;                    // 1.702*log2(e)
    f32x2 u;
    u[0] = __builtin_amdgcn_exp2f(a[0]);
    u[1] = __builtin_amdgcn_exp2f(a[1]);
    f32x2 d = u + 1.0f;
    f32x2 r;
    r[0] = __builtin_amdgcn_rcpf(d[0]);
    r[1] = __builtin_amdgcn_rcpf(d[1]);
    return y * r;
  };

  // LN + GELU postproc for one tile: acc -> H -> af  (f32x2 j-pairs, DPP reductions)
  auto postproc = [&](f32x4 (&acc)[8], short8 (&af)[4],
                      f32x4 glo, f32x4 ghi, f32x4 belo, f32x4 behi){
    f32x2 sA = {0.f, 0.f}, sB = {0.f, 0.f}, qA = {0.f, 0.f}, qB = {0.f, 0.f};
    #pragma unroll
    for (int ct = 0; ct < 8; ++ct){
      f32x2 xy = __builtin_shufflevector(acc[ct], acc[ct], 0, 1);
      f32x2 zw = __builtin_shufflevector(acc[ct], acc[ct], 2, 3);
      sA += xy; qA += xy * xy;
      sB += zw; qB += zw * zw;
    }
    sA[0] = rowsum16(sA[0]); sA[1] = rowsum16(sA[1]);
    sB[0] = rowsum16(sB[0]); sB[1] = rowsum16(sB[1]);
    qA[0] = rowsum16(qA[0]); qA[1] = rowsum16(qA[1]);
    qB[0] = rowsum16(qB[0]); qB[1] = rowsum16(qB[1]);
    f32x2 muA = sA * 0.0078125f, muB = sB * 0.0078125f;
    f32x2 vA = qA * 0.0078125f - muA * muA + 1e-5f;
    f32x2 vB = qB * 0.0078125f - muB * muB + 1e-5f;
    f32x2 rA, rB;
    rA[0] = rsqrtf(vA[0]); rA[1] = rsqrtf(vA[1]);
    rB[0] = rsqrtf(vB[0]); rB[1] = rsqrtf(vB[1]);
    u32x4 ov0, ov1, ov2, ov3;
    #pragma unroll
    for (int p = 0; p < 4; ++p){
      float ga0 = (p < 2) ? glo[2*p]     : ghi[2*p - 4];
      float ga1 = (p < 2) ? glo[2*p + 1] : ghi[2*p - 3];
      float be0 = (p < 2) ? belo[2*p]     : behi[2*p - 4];
      float be1 = (p < 2) ? belo[2*p + 1] : behi[2*p - 3];
      f32x2 xyE = __builtin_shufflevector(acc[2*p],   acc[2*p],   0, 1);
      f32x2 zwE = __builtin_shufflevector(acc[2*p],   acc[2*p],   2, 3);
      f32x2 xyO = __builtin_shufflevector(acc[2*p+1], acc[2*p+1], 0, 1);
      f32x2 zwO = __builtin_shufflevector(acc[2*p+1], acc[2*p+1], 2, 3);
      f32x2 AEA = rA * ga0, AEB = rB * ga0;
      f32x2 AOA = rA * ga1, AOB = rB * ga1;
      f32x2 hEA = gelu2(xyE * AEA + (be0 - muA * AEA));
      f32x2 hEB = gelu2(zwE * AEB + (be0 - muB * AEB));
      f32x2 hOA = gelu2(xyO * AOA + (be1 - muA * AOA));
      f32x2 hOB = gelu2(zwO * AOB + (be1 - muB * AOB));
      unsigned int k0, k1, k2, k3;
      asm("v_cvt_pk_bf16_f32 %0, %1, %2" : "=v"(k0) : "v"(hEA[0]), "v"(hOA[0]));
      asm("v_cvt_pk_bf16_f32 %0, %1, %2" : "=v"(k1) : "v"(hEA[1]), "v"(hOA[1]));
      asm("v_cvt_pk_bf16_f32 %0, %1, %2" : "=v"(k2) : "v"(hEB[0]), "v"(hOB[0]));
      asm("v_cvt_pk_bf16_f32 %0, %1, %2" : "=v"(k3) : "v"(hEB[1]), "v"(hOB[1]));
      ov0[p] = k0; ov1[p] = k1; ov2[p] = k2; ov3[p] = k3;
    }
    int r0 = 4 * g;
    *(u32x4*)(H + (r0 + 0) * 256 + ((c ^ (r0 + 0)) << 4)) = ov0;
    *(u32x4*)(H + (r0 + 1) * 256 + ((c ^ (r0 + 1)) << 4)) = ov1;
    *(u32x4*)(H + (r0 + 2) * 256 + ((c ^ (r0 + 2)) << 4)) = ov2;
    *(u32x4*)(H + (r0 + 3) * 256 + ((c ^ (r0 + 3)) << 4)) = ov3;
    #pragma unroll
    for (int ks = 0; ks < 4; ++ks)
      af[ks] = *(const short8*)(H + c * 256 + (((4 * ks + g) ^ c) << 4));
  };

  // L4 epilogue for one tile (E rows preloaded in regs), f32x2 sigmoid + DPP reduce
  auto epilogue = [&](f32x4 (&acc)[8], short8 (&ep)[4], long rbase){
    f32x2 pgA = {0.f, 0.f}, pgB = {0.f, 0.f};
    #pragma unroll
    for (int ct = 0; ct < 8; ++ct){
      f32x2 xy = __builtin_shufflevector(acc[ct], acc[ct], 0, 1);
      f32x2 zw = __builtin_shufflevector(acc[ct], acc[ct], 2, 3);
      f32x2 aA = xy * -1.4426950f, aB = zw * -1.4426950f;
      f32x2 u, d, r;
      u[0] = __builtin_amdgcn_exp2f(aA[0]); u[1] = __builtin_amdgcn_exp2f(aA[1]);
      d = u + 1.f;
      r[0] = __builtin_amdgcn_rcpf(d[0]); r[1] = __builtin_amdgcn_rcpf(d[1]);
      f32x2 eA = { b2f((unsigned short)ep[0][ct]), b2f((unsigned short)ep[1][ct]) };
      pgA += r * eA;
      u[0] = __builtin_amdgcn_exp2f(aB[0]); u[1] = __builtin_amdgcn_exp2f(aB[1]);
      d = u + 1.f;
      r[0] = __builtin_amdgcn_rcpf(d[0]); r[1] = __builtin_amdgcn_rcpf(d[1]);
      f32x2 eB = { b2f((unsigned short)ep[2][ct]), b2f((unsigned short)ep[3][ct]) };
      pgB += r * eB;
    }
    pgA[0] = rowsum16(pgA[0]); pgA[1] = rowsum16(pgA[1]);
    pgB[0] = rowsum16(pgB[0]); pgB[1] = rowsum16(pgB[1]);
    if (c == 0){
      cbuf[row0 + rbase + 4 * g + 0] = pgA[0];
      cbuf[row0 + rbase + 4 * g + 1] = pgA[1];
      cbuf[row0 + rbase + 4 * g + 2] = pgB[0];
      cbuf[row0 + rbase + 4 * g + 3] = pgB[1];
    }
  };

  stage(0);
  __syncthreads();

  #pragma unroll
  for (int L = 0; L < 3; ++L){
    const float* pp = PPAR + L * 384 + c * 8;
    f32x4 blo  = *(const f32x4*)pp,         bhi  = *(const f32x4*)(pp + 4);
    f32x4 acc0[8], acc1[8];
    mfma2(acc0, acc1, blo, bhi);
    f32x4 glo  = *(const f32x4*)(pp + 128), ghi  = *(const f32x4*)(pp + 132);
    f32x4 belo = *(const f32x4*)(pp + 256), behi = *(const f32x4*)(pp + 260);
    __syncthreads();                       // all waves done reading wbuf
    stage((L + 1) * 16384);                // async DMA next layer, overlaps postproc
    postproc(acc0, af0, glo, ghi, belo, behi);
    postproc(acc1, af1, glo, ghi, belo, behi);
    __syncthreads();                       // drains vmcnt -> wbuf ready
  }

  {
    const float* pp = PPAR + 3 * 384 + c * 8;
    f32x4 blo = *(const f32x4*)pp, bhi = *(const f32x4*)(pp + 4);
    short8 ep0[4], ep1[4];
    #pragma unroll
    for (int j = 0; j < 4; ++j){
      ep0[j] = *(const short8*)(E + (base + 4 * g + j) * ESTR + c * 8);
      ep1[j] = *(const short8*)(E + (base + 64 + 4 * g + j) * ESTR + c * 8);
    }
    f32x4 acc0[8], acc1[8];
    mfma2(acc0, acc1, blo, bhi);
    epilogue(acc0, ep0, base);
    epilogue(acc1, ep1, base + 64);
  }
}

// ---------------- Phase C: affine fold -> Y ----------------
__global__ __launch_bounds__(256) void phaseC(const float* __restrict__ cbuf,
                                              const float* __restrict__ Y0,
                                              float* __restrict__ Yout)
{
  int b = blockIdx.x * 256 + threadIdx.x;
  if (b >= NPATH) return;
  const float kk = 1.0f + 0.05f * (1.0f / 50.0f);   // 1 + R*DT
  float y = Y0[0];
  const float* cb = cbuf + (long)b * NSTEP;
  #pragma unroll 10
  for (int i = 0; i < NSTEP; ++i) y = y * kk + cb[i];
  Yout[b] = y;
}

extern "C" void kernel_launch(void* const* d_in, const int* in_sizes, int n_in,
                              void* d_out, int out_size, void* d_ws, size_t ws_size,
                              hipStream_t stream)
{
  const float* dw  = (const float*)d_in[0];
  const float* tg  = (const float*)d_in[1];
  const float* W1  = (const float*)d_in[2];
  const float* b1  = (const float*)d_in[3];
  const float* g1  = (const float*)d_in[4];
  const float* be1 = (const float*)d_in[5];
  const float* W2  = (const float*)d_in[6];
  const float* b2  = (const float*)d_in[7];
  const float* g2  = (const float*)d_in[8];
  const float* be2 = (const float*)d_in[9];
  const float* W3  = (const float*)d_in[10];
  const float* b3  = (const float*)d_in[11];
  const float* g3  = (const float*)d_in[12];
  const float* be3 = (const float*)d_in[13];
  const float* W4  = (const float*)d_in[14];
  const float* b4  = (const float*)d_in[15];
  const float* Y0  = (const float*)d_in[16];
  float* out = (float*)d_out;               // [0,8192): Y ; [8192,8192+819200): S

  char* ws = (char*)d_ws;
  unsigned short* WTS = (unsigned short*)ws;        // 131072 B
  float* PPAR = (float*)(ws + 131072);              // 1536 * 4 B
  float* cbuf = (float*)(ws + 137344);              // 409600 * 4 B
  char* chunk = ws + 1775744;                       // X/E chunk region (16B aligned)

  prep_all<<<262, 256, 0, stream>>>(W1, W2, W3, W4,
      b1, g1, be1, b2, g2, be2, b3, g3, be3, b4, WTS, PPAR);

  long avail = (long)ws_size - 1775744L;
  long pc = (avail > 0) ? (avail / 25600L) : 0;     // per-path: 12800 (X) + 12800 (E) B
  if (pc > 8192) pc = 8192;
  pc -= pc % 128;                                   // rows multiple of 128
  if (pc < 128) pc = 128;

  for (long p0 = 0; p0 < 8192; p0 += pc){
    long np = 8192 - p0; if (np > pc) np = pc;
    unsigned short* Xc = (unsigned short*)chunk;
    unsigned short* Ec = Xc + np * 50L * XSTR;
    phaseA<<<(int)(np / 4), 256, 0, stream>>>(dw, tg, Xc, Ec, out + 8192, (int)p0);
    long nrows = np * 50L;
    phaseB<<<(int)(nrows / 128), 256, 0, stream>>>(Xc, Ec, WTS, PPAR, cbuf, p0 * 50L);
  }
  phaseC<<<32, 256, 0, stream>>>(cbuf, Y0, out);
}